// Round 3
// baseline (11098.380 us; speedup 1.0000x reference)
//
#include <hip/hip_runtime.h>
#include <math.h>

#define T_  512
#define B_  128
#define H_  256
#define A_  18
#define G4H 1024
#define TB_ (T_*B_)

// d_out layout (floats): [logits T*B*A][baseline T*B][action T*B][hT 2*B*H][cT 2*B*H]
#define OUT_BASE  (TB_*A_)
#define OUT_ACT   (OUT_BASE + TB_)
#define OUT_HT    (OUT_ACT + TB_)
#define OUT_CT    (OUT_HT + 2*B_*H_)

// workspace (floats): double-buffered h per layer (parity = t&1), private c per layer,
// then barrier counter cells (uint32, one per internal barrier instance, memset per replay)
#define WS_H0  0
#define WS_H1  (2*B_*H_)
#define WS_C0  (4*B_*H_)
#define WS_C1  (5*B_*H_)
#define WS_CTR (6*B_*H_)          // 512 uint cells

#define S_    8                   // timesteps per dispatch
#define NDISP 65                  // ceil(514/8)

// MULTI-STEP DISPATCH, v3: 8 lockstep phases per dispatch; the 7 internal phase
// boundaries are device-scope arrive-and-wait barriers (release fence + agent
// atomicAdd + relaxed spin + acquire fence). Co-residency: grid=256=#CUs and
// 135 KB LDS forces 1 WG/CU, so all WGs run simultaneously. Phase semantics are
// identical to the per-dispatch version (lockstep barrier == dispatch boundary),
// parity-2 h buffers stay disjoint within a phase (L0 writes h0(d) parity d&1,
// L1 reads h0(d-1) parity (d-1)&1). Because the acquire invalidates L2 every
// phase, each WG stages its 128 KB weight slice into LDS ONCE per dispatch and
// reads it with ds_read_b128 (16B-stride lanes = 2-way alias, free). Bias, head
// rows and the c-state live in registers across phases.

__global__ __launch_bounds__(512, 1) void lstm_multi(
    const float* __restrict__ x, const int* __restrict__ done,
    const float* __restrict__ h0in, const float* __restrict__ c0in,
    const float* __restrict__ w_ih, const float* __restrict__ w_hh,
    const float* __restrict__ b_ih, const float* __restrict__ b_hh,
    const float* __restrict__ Wp, const float* __restrict__ bp,
    const float* __restrict__ Wb, const float* __restrict__ bb,
    float* __restrict__ out, float* __restrict__ ws, int dsp)
{
    __shared__ __align__(16) float wlds[64*2*H_];      // 128 KB weight slice
    __shared__ __align__(16) float gates[4][16][17];   // 4.25 KB
    __shared__ float hlog[19];

    const int wg   = blockIdx.x;
    const int tid  = threadIdx.x;
    const int l    = wg >> 7;            // 0: layer0, 1: layer1 (+head duty)
    const int wl   = wg & 127;
    const int lane = tid & 63;
    const int w    = tid >> 6;           // wave 0..7
    const int kc   = lane & 15;          // K-chunk owner (16 floats, k = q*64+kc*4)
    const int jq   = lane >> 4;          // batch-quad owner
    const int bt   = wl >> 4, hg = wl & 15, b0 = bt*16;

    // ---- stage weights: 64 gate rows x (wi,wh) -> LDS (coalesced 16B/lane) ----
    {
        const float* WI = w_ih + (size_t)l*G4H*H_;
        const float* WH = w_hh + (size_t)l*G4H*H_;
        float4* dst = (float4*)wlds;
        #pragma unroll
        for (int k = 0; k < 16; ++k) {                  // 8192 float4 / 512 thr
            const int idx = k*512 + tid;
            const int rs = idx >> 7, rem = idx & 127;   // rs: row slot 0..63
            const int m = rem >> 6, q4 = rem & 63;
            const int r = (rs >> 4)*256 + hg*16 + (rs & 15);
            const float* src = (m ? WH : WI) + (size_t)r*H_;
            dst[idx] = ((const float4*)src)[q4];
        }
    }

    // ---- per-thread persistent state across phases ----
    float bsum[8];                                      // bias for my 8 gate rows
    #pragma unroll
    for (int rr = 0; rr < 8; ++rr) {
        const int rs = w*8 + rr;
        const int r  = (rs >> 4)*256 + hg*16 + (rs & 15);
        bsum[rr] = b_ih[(size_t)l*G4H + r] + b_hh[(size_t)l*G4H + r];
    }
    float4 wpr[3]; float wpb[3];                        // head rows w, w+8, w+16
    if (l == 1) {
        #pragma unroll
        for (int k = 0; k < 3; ++k) {
            const int a = w + 8*k;
            if (a < 19) {
                const float* wr = (a < 18) ? (Wp + (size_t)a*H_) : Wb;
                wpr[k] = ((const float4*)wr)[lane];
                wpb[k] = (a < 18) ? bp[a] : bb[0];
            }
        }
    }
    float cr = 0.f; bool chave = false;                 // c-state in register (owner-private)

    unsigned int* ctr = (unsigned int*)(ws + WS_CTR);
    __syncthreads();                                    // weights staged

    for (int p = 0; p < S_; ++p) {
        const int d = dsp*S_ + p;
        const int t = d - l;
        const bool work   = (t >= 0 && t < T_);
        const bool dohead = (l == 1 && d >= 2 && d - 2 < T_);

        // ---- head part 1 for t = d-2 (reads h1 written 2 phases ago) ----
        if (dohead) {
            const int th = d - 2;
            const float* h1p = ws + WS_H1 + (size_t)(th & 1)*B_*H_ + (size_t)wl*H_;
            float4 h4 = ((const float4*)h1p)[lane];
            #pragma unroll
            for (int k = 0; k < 3; ++k) {
                const int a = w + 8*k;
                if (a < 19) {
                    float s = wpr[k].x*h4.x + wpr[k].y*h4.y + wpr[k].z*h4.z + wpr[k].w*h4.w;
                    s += __shfl_xor(s, 1);  s += __shfl_xor(s, 2);  s += __shfl_xor(s, 4);
                    s += __shfl_xor(s, 8);  s += __shfl_xor(s, 16); s += __shfl_xor(s, 32);
                    if (lane == 0) {
                        float v = s + wpb[k];
                        hlog[a] = v;
                        if (a < 18) out[((size_t)th*B_ + wl)*A_ + a] = v;
                        else        out[OUT_BASE + th*B_ + wl] = v;
                    }
                }
            }
        }

        // ---- gate phase (weights from LDS) ----
        if (work) {
            const float* hrec = (t == 0) ? (h0in + (size_t)l*B_*H_)
                                         : (ws + (l ? WS_H1 : WS_H0) + (size_t)((t-1)&1)*B_*H_);
            const float* xin  = l ? (ws + WS_H0 + (size_t)(t&1)*B_*H_)
                                  : (x + (size_t)t*B_*H_);
            float4 xr[4][4], hr[4][4];
            #pragma unroll
            for (int jj = 0; jj < 4; ++jj) {
                const int b = b0 + jq*4 + jj;
                const float nd = done[t*B_ + b] ? 0.f : 1.f;
                const float4* xb = (const float4*)(xin  + (size_t)b*H_);
                const float4* hb = (const float4*)(hrec + (size_t)b*H_);
                #pragma unroll
                for (int q = 0; q < 4; ++q) {
                    xr[jj][q] = xb[q*16 + kc];
                    float4 h4 = hb[q*16 + kc];
                    hr[jj][q] = make_float4(h4.x*nd, h4.y*nd, h4.z*nd, h4.w*nd);
                }
            }
            const float4* wl4 = (const float4*)wlds;
            #pragma unroll 2
            for (int rr = 0; rr < 8; ++rr) {
                const int rs = w*8 + rr;
                const int g  = rs >> 4, ri = rs & 15;
                const int wb4 = rs*128;                 // 2 mats * 64 float4
                float4 wiv[4], whv[4];
                #pragma unroll
                for (int q = 0; q < 4; ++q) {
                    wiv[q] = wl4[wb4 + q*16 + kc];
                    whv[q] = wl4[wb4 + 64 + q*16 + kc];
                }
                float acc0 = 0.f, acc1 = 0.f, acc2 = 0.f, acc3 = 0.f;
                #pragma unroll
                for (int q = 0; q < 4; ++q) {
                    acc0 += wiv[q].x*xr[0][q].x + wiv[q].y*xr[0][q].y + wiv[q].z*xr[0][q].z + wiv[q].w*xr[0][q].w
                          + whv[q].x*hr[0][q].x + whv[q].y*hr[0][q].y + whv[q].z*hr[0][q].z + whv[q].w*hr[0][q].w;
                    acc1 += wiv[q].x*xr[1][q].x + wiv[q].y*xr[1][q].y + wiv[q].z*xr[1][q].z + wiv[q].w*xr[1][q].w
                          + whv[q].x*hr[1][q].x + whv[q].y*hr[1][q].y + whv[q].z*hr[1][q].z + whv[q].w*hr[1][q].w;
                    acc2 += wiv[q].x*xr[2][q].x + wiv[q].y*xr[2][q].y + wiv[q].z*xr[2][q].z + wiv[q].w*xr[2][q].w
                          + whv[q].x*hr[2][q].x + whv[q].y*hr[2][q].y + whv[q].z*hr[2][q].z + whv[q].w*hr[2][q].w;
                    acc3 += wiv[q].x*xr[3][q].x + wiv[q].y*xr[3][q].y + wiv[q].z*xr[3][q].z + wiv[q].w*xr[3][q].w
                          + whv[q].x*hr[3][q].x + whv[q].y*hr[3][q].y + whv[q].z*hr[3][q].z + whv[q].w*hr[3][q].w;
                }
                acc0 += __shfl_xor(acc0, 1, 16); acc0 += __shfl_xor(acc0, 2, 16);
                acc0 += __shfl_xor(acc0, 4, 16); acc0 += __shfl_xor(acc0, 8, 16);
                acc1 += __shfl_xor(acc1, 1, 16); acc1 += __shfl_xor(acc1, 2, 16);
                acc1 += __shfl_xor(acc1, 4, 16); acc1 += __shfl_xor(acc1, 8, 16);
                acc2 += __shfl_xor(acc2, 1, 16); acc2 += __shfl_xor(acc2, 2, 16);
                acc2 += __shfl_xor(acc2, 4, 16); acc2 += __shfl_xor(acc2, 8, 16);
                acc3 += __shfl_xor(acc3, 1, 16); acc3 += __shfl_xor(acc3, 2, 16);
                acc3 += __shfl_xor(acc3, 4, 16); acc3 += __shfl_xor(acc3, 8, 16);
                float v = (kc == 0) ? acc0 : (kc == 1) ? acc1 : (kc == 2) ? acc2 : acc3;
                if (kc < 4)
                    gates[g][ri][jq*4 + kc] = v + bsum[rr];
            }
        }

        __syncthreads();          // gates ready (uniform)

        // ---- cell update: 256 (batch, h) pairs; c stays in a register ----
        if (work && tid < 256) {
            const int j = tid >> 4, hi = tid & 15;
            const int b = b0 + j, h = hg*16 + hi;
            const float nd = done[t*B_ + b] ? 0.f : 1.f;
            float* cst = ws + (l ? WS_C1 : WS_C0) + (size_t)b*H_ + h;
            if (!chave) {
                cr = (t == 0) ? c0in[(size_t)l*B_*H_ + b*H_ + h] : *cst;
                chave = true;
            }
            float cp = cr * nd;
            const float gi = gates[0][hi][j], gf = gates[1][hi][j];
            const float gv = gates[2][hi][j], go = gates[3][hi][j];
            const float ii = 1.f/(1.f + expf(-gi));
            const float ff = 1.f/(1.f + expf(-gf));
            const float gt = tanhf(gv);
            const float oo = 1.f/(1.f + expf(-go));
            const float cl = ff*cp + ii*gt;
            cr = cl;
            *cst = cl;                                   // visible via phase barrier
            float* hout = ws + (l ? WS_H1 : WS_H0) + (size_t)(t&1)*B_*H_;
            hout[(size_t)b*H_ + h] = oo*tanhf(cl);
        }

        // ---- argmax (hlog complete; ordered by the mid __syncthreads) ----
        if (dohead && tid == 0) {
            const int th = d - 2;
            float best = hlog[0]; int bi = 0;
            #pragma unroll
            for (int a = 1; a < A_; ++a) { float v = hlog[a]; if (v > best) { best = v; bi = a; } }
            out[OUT_ACT + th*B_ + wl] = (float)bi;       // strict > = first-max, matches np
        }

        // ---- final state copy (reads this dispatch's p=0 writes via barrier) ----
        if (l == 1 && d == 513 && tid < 256) {
            const int idx = wl*H_ + tid;
            out[OUT_HT + idx]         = ws[WS_H0 + B_*H_ + idx];   // h(511) parity 1
            out[OUT_HT + B_*H_ + idx] = ws[WS_H1 + B_*H_ + idx];
            out[OUT_CT + idx]         = ws[WS_C0 + idx];
            out[OUT_CT + B_*H_ + idx] = ws[WS_C1 + idx];
        }

        if (d >= 513) break;       // uniform across the grid; no cells beyond this

        // ---- device-scope phase barrier (internal phases only) ----
        if (p < S_ - 1) {
            __syncthreads();       // all waves' stores drained past the CU (vmcnt 0)
            if (tid == 0) {
                unsigned int* cell = ctr + (dsp*(S_-1) + p);
                __builtin_amdgcn_fence(__ATOMIC_RELEASE, "agent");      // L2 writeback
                __hip_atomic_fetch_add(cell, 1u, __ATOMIC_RELAXED, __HIP_MEMORY_SCOPE_AGENT);
                while (__hip_atomic_load(cell, __ATOMIC_RELAXED, __HIP_MEMORY_SCOPE_AGENT) < 256u)
                    __builtin_amdgcn_s_sleep(2);
                __builtin_amdgcn_fence(__ATOMIC_ACQUIRE, "agent");      // L1/L2 invalidate
            }
            __syncthreads();
        }
    }
}

extern "C" void kernel_launch(void* const* d_in, const int* in_sizes, int n_in,
                              void* d_out, int out_size, void* d_ws, size_t ws_size,
                              hipStream_t stream)
{
    const float* x    = (const float*)d_in[0];
    const int*   done = (const int*)  d_in[1];
    const float* h0   = (const float*)d_in[2];
    const float* c0   = (const float*)d_in[3];
    const float* w_ih = (const float*)d_in[4];
    const float* w_hh = (const float*)d_in[5];
    const float* b_ih = (const float*)d_in[6];
    const float* b_hh = (const float*)d_in[7];
    const float* Wp   = (const float*)d_in[8];
    const float* bp   = (const float*)d_in[9];
    const float* Wb   = (const float*)d_in[10];
    const float* bb   = (const float*)d_in[11];
    float* out = (float*)d_out;
    float* ws  = (float*)d_ws;    // 6*B*H floats state + 2 KB barrier cells

    // zero the barrier cells (captured node, re-runs every replay)
    hipMemsetAsync((char*)d_ws + (size_t)WS_CTR*sizeof(float), 0, 2048, stream);

    for (int dsp = 0; dsp < NDISP; ++dsp) {
        lstm_multi<<<dim3(256), dim3(512), 0, stream>>>(
            x, done, h0, c0, w_ih, w_hh, b_ih, b_hh, Wp, bp, Wb, bb, out, ws, dsp);
    }
}